// Round 1
// baseline (123.453 us; speedup 1.0000x reference)
//
#include <hip/hip_runtime.h>

#define NG 512
#define WI 256
#define HI 256
#define FXc 256.0f   // W / (2*tanfovx)
#define FYc 256.0f   // H / (2*tanfovy)

// -------------------- kernel 1: per-Gaussian preprocess --------------------
// Writes packed record per gaussian into ws_u (12 floats):
//   [mx, my, A, B,  C, op_eff, colR, colG,  colB, tz, 0, 0]
// plus ws_tz[] (sort key) and radii (as float) into the tail of d_out.
__global__ void gs_preprocess(
    const float* __restrict__ means,
    const float* __restrict__ opac,
    const float* __restrict__ cols,
    const float* __restrict__ scales,
    const float* __restrict__ rots,
    const float* __restrict__ Vm,   // viewmatrix, row-major 4x4
    const float* __restrict__ Pm,   // projmatrix (V@P), row-major 4x4
    float* __restrict__ ws_u,
    float* __restrict__ ws_tz,
    float* __restrict__ radii_out)
{
    int g = blockIdx.x * blockDim.x + threadIdx.x;
    if (g >= NG) return;

    // quaternion -> rotation
    float qr = rots[g*4+0], qx = rots[g*4+1], qy = rots[g*4+2], qz = rots[g*4+3];
    float inv = rsqrtf(qr*qr + qx*qx + qy*qy + qz*qz);
    qr *= inv; qx *= inv; qy *= inv; qz *= inv;
    float R00 = 1.f - 2.f*(qy*qy + qz*qz);
    float R01 = 2.f*(qx*qy - qr*qz);
    float R02 = 2.f*(qx*qz + qr*qy);
    float R10 = 2.f*(qx*qy + qr*qz);
    float R11 = 1.f - 2.f*(qx*qx + qz*qz);
    float R12 = 2.f*(qy*qz - qr*qx);
    float R20 = 2.f*(qx*qz - qr*qy);
    float R21 = 2.f*(qy*qz + qr*qx);
    float R22 = 1.f - 2.f*(qx*qx + qy*qy);

    // M = R * diag-ish broadcast of scales over columns
    float s0 = scales[g*3+0], s1 = scales[g*3+1], s2 = scales[g*3+2];
    float M00=R00*s0, M01=R01*s1, M02=R02*s2;
    float M10=R10*s0, M11=R11*s1, M12=R12*s2;
    float M20=R20*s0, M21=R21*s1, M22=R22*s2;

    // Sigma = M * M^T (symmetric)
    float S00 = M00*M00 + M01*M01 + M02*M02;
    float S01 = M00*M10 + M01*M11 + M02*M12;
    float S02 = M00*M20 + M01*M21 + M02*M22;
    float S11 = M10*M10 + M11*M11 + M12*M12;
    float S12 = M10*M20 + M11*M21 + M12*M22;
    float S22 = M20*M20 + M21*M21 + M22*M22;

    // t = [p,1] @ V (row-vector times row-major matrix)
    float px = means[g*3+0], py = means[g*3+1], pz = means[g*3+2];
    float t0 = px*Vm[0] + py*Vm[4] + pz*Vm[8]  + Vm[12];
    float t1 = px*Vm[1] + py*Vm[5] + pz*Vm[9]  + Vm[13];
    float t2 = px*Vm[2] + py*Vm[6] + pz*Vm[10] + Vm[14];
    float tz = t2;
    float tzc = fmaxf(tz, 1e-4f);
    const float limx = 1.3f*0.5f, limy = 1.3f*0.5f;
    float txc = fminf(fmaxf(t0 / tzc, -limx), limx) * tzc;
    float tyc = fminf(fmaxf(t1 / tzc, -limy), limy) * tzc;

    float J00 = FXc / tzc;
    float J02 = -FXc * txc / (tzc * tzc);
    float J11 = FYc / tzc;
    float J12 = -FYc * tyc / (tzc * tzc);

    // T2[i][k] = sum_j J[i][j] * Wc[j][k], Wc = V[:3,:3]^T -> Wc[j][k] = V[k][j]
    float Ta0 = J00*Vm[0] + J02*Vm[2];
    float Ta1 = J00*Vm[4] + J02*Vm[6];
    float Ta2 = J00*Vm[8] + J02*Vm[10];
    float Tb0 = J11*Vm[1] + J12*Vm[2];
    float Tb1 = J11*Vm[5] + J12*Vm[6];
    float Tb2 = J11*Vm[9] + J12*Vm[10];

    // cov2d = T2 * Sigma * T2^T + 0.3*I
    float u0 = Ta0*S00 + Ta1*S01 + Ta2*S02;
    float u1 = Ta0*S01 + Ta1*S11 + Ta2*S12;
    float u2 = Ta0*S02 + Ta1*S12 + Ta2*S22;
    float v0 = Tb0*S00 + Tb1*S01 + Tb2*S02;
    float v1 = Tb0*S01 + Tb1*S11 + Tb2*S12;
    float v2 = Tb0*S02 + Tb1*S12 + Tb2*S22;
    float c00 = u0*Ta0 + u1*Ta1 + u2*Ta2 + 0.3f;
    float c01 = u0*Tb0 + u1*Tb1 + u2*Tb2;
    float c11 = v0*Tb0 + v1*Tb1 + v2*Tb2 + 0.3f;

    float det = c00*c11 - c01*c01;
    float det_inv = 1.f / ((det != 0.f) ? det : 1.f);
    float Aa =  c11 * det_inv;
    float Bb = -c01 * det_inv;
    float Cc =  c00 * det_inv;

    float mid = 0.5f*(c00 + c11);
    float lam = mid + sqrtf(fmaxf(mid*mid - det, 0.1f));
    bool vis = (det > 0.f) && (tz > 0.2f);
    int rad = vis ? (int)ceilf(3.f*sqrtf(lam)) : 0;
    radii_out[g] = (float)rad;   // whole d_out buffer is read back as f32

    // screen-space mean via projmatrix
    float h0 = px*Pm[0] + py*Pm[4] + pz*Pm[8]  + Pm[12];
    float h1 = px*Pm[1] + py*Pm[5] + pz*Pm[9]  + Pm[13];
    float h3 = px*Pm[3] + py*Pm[7] + pz*Pm[11] + Pm[15];
    float pw = 1.f / (h3 + 1e-7f);
    float mx = ((h0*pw + 1.f)*WI - 1.f)*0.5f;
    float my = ((h1*pw + 1.f)*HI - 1.f)*0.5f;

    // visibility folded into opacity: op=0 => alpha=0 < 1/255 => invalid
    float opv = vis ? opac[g] : 0.f;

    float* u = ws_u + g*12;
    u[0]=mx;  u[1]=my;  u[2]=Aa;          u[3]=Bb;
    u[4]=Cc;  u[5]=opv; u[6]=cols[g*3+0]; u[7]=cols[g*3+1];
    u[8]=cols[g*3+2]; u[9]=tz; u[10]=0.f; u[11]=0.f;
    ws_tz[g] = tz;
}

// -------------------- kernel 2: stable rank sort by tz --------------------
__global__ void gs_sort(const float* __restrict__ ws_u,
                        const float* __restrict__ ws_tz,
                        float* __restrict__ ws_s)
{
    __shared__ float key[NG];
    int i = threadIdx.x;
    key[i] = ws_tz[i];
    __syncthreads();
    float k = key[i];
    int rank = 0;
    for (int j = 0; j < NG; ++j) {
        float o = key[j];
        rank += (o < k) || (o == k && j < i);   // stable tie-break = argsort(kind=stable)
    }
    const float4* src = (const float4*)(ws_u + i*12);
    float4* dst = (float4*)(ws_s + rank*12);
    dst[0] = src[0]; dst[1] = src[1]; dst[2] = src[2];
}

// -------------------- kernel 3: per-pixel front-to-back blend --------------------
__global__ __launch_bounds__(256) void gs_raster(
    const float* __restrict__ ws_s,
    const float* __restrict__ bg,
    float* __restrict__ out)
{
    __shared__ float4 sg[NG*3];   // 24 KB: all 512 sorted gaussians
    const float4* gsrc = (const float4*)ws_s;
    for (int i = threadIdx.x; i < NG*3; i += 256) sg[i] = gsrc[i];
    __syncthreads();

    float pxf = (float)threadIdx.x;   // pixel x
    float pyf = (float)blockIdx.x;    // pixel y (one block per row)

    float T = 1.f, cr = 0.f, cg = 0.f, cb = 0.f, dep = 0.f;
    #pragma unroll 4
    for (int g = 0; g < NG; ++g) {
        float4 a = sg[g*3+0];   // mx, my, A, B   (wave-uniform broadcast reads)
        float4 b = sg[g*3+1];   // C, op, colR, colG
        float4 c = sg[g*3+2];   // colB, tz, -, -
        float dx = a.x - pxf;
        float dy = a.y - pyf;
        float pwr = -0.5f*(a.z*dx*dx + b.x*dy*dy) - a.w*dx*dy;
        float alpha = fminf(0.99f, b.y * __expf(pwr));
        bool valid = (pwr <= 0.f) && (alpha >= (1.f/255.f));
        alpha = valid ? alpha : 0.f;
        float w = alpha * T;
        cr  += w * b.z;
        cg  += w * b.w;
        cb  += w * c.x;
        dep += w * c.y;
        T = T * (1.f - alpha);
    }

    int p = blockIdx.x * WI + threadIdx.x;
    const int HW = WI * HI;
    out[p]        = cr + T * bg[0];
    out[HW+p]     = cg + T * bg[1];
    out[2*HW+p]   = cb + T * bg[2];
    out[3*HW+p]   = dep;
    out[4*HW+p]   = T;
}

extern "C" void kernel_launch(void* const* d_in, const int* in_sizes, int n_in,
                              void* d_out, int out_size, void* d_ws, size_t ws_size,
                              hipStream_t stream)
{
    const float* means  = (const float*)d_in[0];
    const float* opac   = (const float*)d_in[1];
    const float* cols   = (const float*)d_in[2];
    const float* scales = (const float*)d_in[3];
    const float* rots   = (const float*)d_in[4];
    const float* bg     = (const float*)d_in[5];
    const float* Vm     = (const float*)d_in[6];
    const float* Pm     = (const float*)d_in[7];
    // d_in[8] = campos (unused by reference math)

    float* out = (float*)d_out;
    float* ws  = (float*)d_ws;
    float* ws_u  = ws;             // 12*NG floats, unsorted packed
    float* ws_tz = ws + 12*NG;     // NG floats, sort keys
    float* ws_s  = ws + 13*NG;     // 12*NG floats, sorted packed
    float* radii_out = out + 5*WI*HI;  // after color(3HW)+depth(HW)+Tfinal(HW)

    hipLaunchKernelGGL(gs_preprocess, dim3((NG+255)/256), dim3(256), 0, stream,
                       means, opac, cols, scales, rots, Vm, Pm, ws_u, ws_tz, radii_out);
    hipLaunchKernelGGL(gs_sort, dim3(1), dim3(NG), 0, stream, ws_u, ws_tz, ws_s);
    hipLaunchKernelGGL(gs_raster, dim3(HI), dim3(WI), 0, stream, ws_s, bg, out);
}